// Round 2
// baseline (190.486 us; speedup 1.0000x reference)
//
#include <hip/hip_runtime.h>
#include <stdint.h>

// FFM: B=4096, F=20 fields x S=500 feats, K=16.
// E[b,g,i,k] = sum_s x[b,i*500+s] * v[g,i*500+s,k]   (20 GEMMs [B,500]x[500,320])
// out[b] = x[b,:]@w + sum_{i<j} sum_k E[b,j,i,k]*E[b,i,j,k]

#define NF 20
#define FS 500
#define TFEAT 10000
#define KD 16
#define NC 320          // NF*KD, GEMM N
#define KP 512          // K padded to mult of 64
#define NB 4096

typedef __bf16 bf16x8 __attribute__((ext_vector_type(8)));
typedef __bf16 bf16x4 __attribute__((ext_vector_type(4)));
typedef __bf16 bf16x2 __attribute__((ext_vector_type(2)));
typedef float  f32x4  __attribute__((ext_vector_type(4)));
typedef unsigned int u32x4 __attribute__((ext_vector_type(4)));

// ---------------- prep: Vt[i][n][kk] = v[g, i*500+kk, k], n=g*16+k, kk<512 (0-padded)
__global__ __launch_bounds__(256) void prep_vt(const float* __restrict__ v,
                                               __bf16* __restrict__ Vt) {
  __shared__ float lv[FS * 17];  // +1 pad breaks bank conflicts on transposed read
  const int i = blockIdx.x / NF;
  const int g = blockIdx.x % NF;
  const int t = threadIdx.x;
  const int k = t & 15, sb = t >> 4;
  const float* vb = v + ((size_t)g * TFEAT + (size_t)i * FS) * KD;
  for (int it = 0; it < 32; ++it) {
    int s = it * 16 + sb;
    if (s < FS) lv[s * 17 + k] = vb[(size_t)s * KD + k];
  }
  __syncthreads();
  __bf16* out = Vt + ((size_t)(i * NC + g * 16)) * KP;
  for (int r = 0; r < 16; ++r) {
    int s0 = 2 * t, s1 = 2 * t + 1;
    bf16x2 pr;
    pr[0] = (s0 < FS) ? (__bf16)lv[s0 * 17 + r] : (__bf16)0.f;
    pr[1] = (s1 < FS) ? (__bf16)lv[s1 * 17 + r] : (__bf16)0.f;
    *(bf16x2*)(out + (size_t)r * KP + 2 * t) = pr;
  }
}

// ---------------- K1: per-field GEMM + fused linear partial
// grid = NF * tiles (tiles = Bc/64), block 256 = 4 waves side-by-side in N.
// BM=64, BN=320, BK=64. Wave tile 64x80 -> acc[4][5].
// A: double-buffered LDS (reg-staged, padded stride 72, f32->bf16 at stage).
// B: direct global->VGPR fragment loads from L2-resident Vt (no LDS, no barrier coupling).
// Barriers: raw s_barrier + lgkmcnt(0) only -- A-prefetch vmcnt stays in flight.
__global__ __launch_bounds__(256, 2) void k1_gemm(
    const float* __restrict__ x, const float* __restrict__ w,
    const __bf16* __restrict__ Vt, __bf16* __restrict__ E,
    float* __restrict__ lin, int chunk_base, int tiles) {
  __shared__ __align__(16) __bf16 As[2][64][72];

  const int bx = blockIdx.x;
  const int i  = bx / tiles;        // field
  const int tb = bx % tiles;        // batch tile
  const int tid = threadIdx.x;
  const int lane = tid & 63, wid = tid >> 6;   // wid = N-quadrant (80 cols each)

  const int b0 = chunk_base + tb * 64;
  const int arow = tid >> 2;                   // 0..63 (A-stage row)
  const int acol0 = (tid & 3) * 4;             // f32 col base within 16-col group
  const float* xrow = x + (size_t)(b0 + arow) * TFEAT + i * FS;
  const float* wcol = w + i * FS;
  const __bf16* vbase =
      Vt + ((size_t)i * NC + wid * 80 + (lane & 15)) * KP + (lane >> 4) * 8;

  float lp = 0.f;
  f32x4 acc[4][5];
#pragma unroll
  for (int m = 0; m < 4; ++m)
#pragma unroll
    for (int nf = 0; nf < 5; ++nf) acc[m][nf] = (f32x4){0.f, 0.f, 0.f, 0.f};
  f32x4 ar[4];

  auto loadA = [&](int t) {
#pragma unroll
    for (int j = 0; j < 4; ++j) {
      int c = t * 64 + acol0 + j * 16;
      ar[j] = (c < FS) ? *(const f32x4*)(xrow + c) : (f32x4){0.f, 0.f, 0.f, 0.f};
    }
  };
  auto storeA = [&](int buf, int t) {
#pragma unroll
    for (int j = 0; j < 4; ++j) {
      int c = t * 64 + acol0 + j * 16;
      if (c < FS) {
        f32x4 wv = *(const f32x4*)(wcol + c);
        lp += ar[j][0] * wv[0] + ar[j][1] * wv[1] + ar[j][2] * wv[2] + ar[j][3] * wv[3];
      }
      bf16x4 h;
      h[0] = (__bf16)ar[j][0]; h[1] = (__bf16)ar[j][1];
      h[2] = (__bf16)ar[j][2]; h[3] = (__bf16)ar[j][3];
      *(bf16x4*)(&As[buf][arow][acol0 + j * 16]) = h;
    }
  };

  // prologue: tile0 staged, tile1 prefetch in flight
  loadA(0);
  storeA(0, 0);
  loadA(1);
  asm volatile("s_waitcnt lgkmcnt(0)" ::: "memory");
  __builtin_amdgcn_s_barrier();
  __builtin_amdgcn_sched_barrier(0);

  for (int t = 0; t < 8; ++t) {
    const int cur = t & 1;
    // B fragments for this K-tile: straight from global (L2). vmcnt-dep only.
    bf16x8 bf[2][5];
#pragma unroll
    for (int ks = 0; ks < 2; ++ks)
#pragma unroll
      for (int nf = 0; nf < 5; ++nf)
        bf[ks][nf] = *(const bf16x8*)(vbase + (size_t)nf * (16 * KP) + t * 64 + ks * 32);
#pragma unroll
    for (int ks = 0; ks < 2; ++ks) {
      bf16x8 af[4];
#pragma unroll
      for (int m = 0; m < 4; ++m)
        af[m] = *(const bf16x8*)(&As[cur][m * 16 + (lane & 15)][ks * 32 + (lane >> 4) * 8]);
#pragma unroll
      for (int nf = 0; nf < 5; ++nf)
#pragma unroll
        for (int m = 0; m < 4; ++m)
          acc[m][nf] = __builtin_amdgcn_mfma_f32_16x16x32_bf16(af[m], bf[ks][nf],
                                                               acc[m][nf], 0, 0, 0);
    }
    if (t < 7) {
      storeA(cur ^ 1, t + 1);      // cvt (waits its own vmcnt) + ds_write other buffer
      if (t < 6) loadA(t + 2);     // issue next prefetch; stays in flight across barrier
      asm volatile("s_waitcnt lgkmcnt(0)" ::: "memory");
      __builtin_amdgcn_s_barrier();
      __builtin_amdgcn_sched_barrier(0);
    }
  }

  // linear partial: 4 threads share a row
  lp += __shfl_xor(lp, 1);
  lp += __shfl_xor(lp, 2);
  if ((lane & 3) == 0) atomicAdd(&lin[b0 + arow], lp);

  // epilogue: E[b_local][i*320+n], C/D layout col=lane&15, row=(lane>>4)*4+r
  const int lrow4 = (lane >> 4) * 4, lcol = lane & 15;
#pragma unroll
  for (int m = 0; m < 4; ++m)
#pragma unroll
    for (int nf = 0; nf < 5; ++nf) {
      int n = wid * 80 + nf * 16 + lcol;
#pragma unroll
      for (int r = 0; r < 4; ++r) {
        int bl = tb * 64 + m * 16 + lrow4 + r;
        E[(size_t)bl * (NF * NC) + i * NC + n] = (__bf16)acc[m][nf][r];
      }
    }
}

// ---------------- K2: pair reduction, 1 wave per batch row
__global__ __launch_bounds__(256) void k2_pair(
    const __bf16* __restrict__ E, const float* __restrict__ lin,
    float* __restrict__ out, int chunk_base) {
  __shared__ __align__(16) unsigned shw[4][3200];  // 12.8KB per wave
  const int tid = threadIdx.x, lane = tid & 63, wid = tid >> 6;
  const int bl = blockIdx.x * 4 + wid;             // chunk-local row
  const unsigned* src = (const unsigned*)(E + (size_t)bl * (NF * NC));
  for (int it = 0; it < 13; ++it) {
    int idx = it * 64 + lane;                      // 16B units
    if (idx < 800) {
      u32x4 val = *(const u32x4*)(src + (size_t)idx * 4);
      *(u32x4*)&shw[wid][idx * 4] = val;
    }
  }
  __syncthreads();
  const __bf16* sh = (const __bf16*)shw[wid];
  const int k = lane & 15, g = lane >> 4;
  float sum = 0.f;
  for (int i = g; i < NF; i += 4)
    for (int j = i + 1; j < NF; ++j)
      sum += (float)sh[i * NC + j * 16 + k] * (float)sh[j * NC + i * 16 + k];
#pragma unroll
  for (int off = 32; off; off >>= 1) sum += __shfl_xor(sum, off);
  if (lane == 0) {
    int bg = chunk_base + bl;
    out[bg] = lin[bg] + sum;
  }
}

extern "C" void kernel_launch(void* const* d_in, const int* in_sizes, int n_in,
                              void* d_out, int out_size, void* d_ws, size_t ws_size,
                              hipStream_t stream) {
  const float* x = (const float*)d_in[0];
  const float* w = (const float*)d_in[1];
  const float* v = (const float*)d_in[2];
  float* out = (float*)d_out;
  char* ws = (char*)d_ws;

  __bf16* Vt = (__bf16*)ws;                                // 20*320*512*2 = 6,553,600 B
  float* lin = (float*)(ws + 6553600);                     // 16,384 B
  __bf16* E  = (__bf16*)(ws + 6553600 + 16384);            // Bc*6400*2 B

  size_t eavail = (ws_size > 6569984) ? ws_size - 6569984 : 0;
  int Bc = NB;
  while (Bc > 128 && (size_t)Bc * (NF * NC) * 2 > eavail) Bc >>= 1;

  hipMemsetAsync(lin, 0, NB * sizeof(float), stream);
  prep_vt<<<NF * NF, 256, 0, stream>>>(v, Vt);
  for (int cb = 0; cb < NB; cb += Bc) {
    int tiles = Bc / 64;
    k1_gemm<<<NF * tiles, 256, 0, stream>>>(x, w, Vt, E, lin, cb, tiles);
    k2_pair<<<Bc / 4, 256, 0, stream>>>(E, lin, out, cb);
  }
}